// Round 3
// baseline (406.754 us; speedup 1.0000x reference)
//
#include <hip/hip_runtime.h>

#define E     1024
#define HEADS 16
#define HD    64
#define FFD   4096
#define TT    2048
#define MMDIM 4096   // B*T

typedef __bf16 bf16x8 __attribute__((ext_vector_type(8)));
typedef float f32x4 __attribute__((ext_vector_type(4)));
typedef float f32x16 __attribute__((ext_vector_type(16)));
typedef unsigned short u16;
typedef unsigned u32;
typedef u16 ushort8 __attribute__((ext_vector_type(8)));
typedef u16 us4 __attribute__((ext_vector_type(4)));
typedef u32 u32x4 __attribute__((ext_vector_type(4)));

__device__ __forceinline__ u16 f2bf(float f) {
  unsigned u = __float_as_uint(f);
  u = (u + 0x7fffu + ((u >> 16) & 1u)) >> 16;
  return (u16)u;
}
__device__ __forceinline__ float bf2f(u16 u) {
  return __uint_as_float(((unsigned)u) << 16);
}
__device__ __forceinline__ u32 cvtpk(float a, float b) {
  u32 r;
  asm("v_cvt_pk_bf16_f32 %0, %1, %2" : "=v"(r) : "v"(a), "v"(b));
  return r;
}

__device__ __forceinline__ void gload_lds16(const void* g, void* l) {
  __builtin_amdgcn_global_load_lds((__attribute__((address_space(1))) void*)g,
                                   (__attribute__((address_space(3))) void*)l,
                                   16, 0, 0);
}

// ---------------- LayerNorm: fp32 in -> bf16 out ----------------
__global__ void __launch_bounds__(256) ln_kernel(const float* __restrict__ x,
                                                 const float* __restrict__ g,
                                                 const float* __restrict__ b,
                                                 u16* __restrict__ out) {
  int row = blockIdx.x;
  int t = threadIdx.x;
  const float4 v = reinterpret_cast<const float4*>(x + (size_t)row * E)[t];
  float s = v.x + v.y + v.z + v.w;
  float s2 = v.x * v.x + v.y * v.y + v.z * v.z + v.w * v.w;
#pragma unroll
  for (int m = 1; m < 64; m <<= 1) {
    s += __shfl_xor(s, m);
    s2 += __shfl_xor(s2, m);
  }
  __shared__ float red[8];
  int wave = t >> 6, lane = t & 63;
  if (lane == 0) { red[wave] = s; red[wave + 4] = s2; }
  __syncthreads();
  s = red[0] + red[1] + red[2] + red[3];
  s2 = red[4] + red[5] + red[6] + red[7];
  float mean = s * (1.f / E);
  float var = s2 * (1.f / E) - mean * mean;
  float inv = rsqrtf(var + 1e-5f);
  const float4 gv = reinterpret_cast<const float4*>(g)[t];
  const float4 bv = reinterpret_cast<const float4*>(b)[t];
  us4 pk;
  pk.x = f2bf((v.x - mean) * inv * gv.x + bv.x);
  pk.y = f2bf((v.y - mean) * inv * gv.y + bv.y);
  pk.z = f2bf((v.z - mean) * inv * gv.z + bv.z);
  pk.w = f2bf((v.w - mean) * inv * gv.w + bv.w);
  *(us4*)(out + (size_t)row * E + t * 4) = pk;
}

// ------------- Transpose+convert: W[K,N] fp32 -> Wt[N,K] bf16 -------------
__global__ void __launch_bounds__(256) transpose_bf16(const float* __restrict__ in,
                                                      u16* __restrict__ out,
                                                      int K, int N) {
  __shared__ float tile[32][33];
  int k0 = blockIdx.y * 32, n0 = blockIdx.x * 32;
  int tx = threadIdx.x, ty = threadIdx.y;  // block (32,8)
#pragma unroll
  for (int i = ty; i < 32; i += 8)
    tile[i][tx] = in[(size_t)(k0 + i) * N + n0 + tx];
  __syncthreads();
#pragma unroll
  for (int i = ty; i < 32; i += 8)
    out[(size_t)(n0 + i) * K + k0 + tx] = f2bf(tile[tx][i]);
}

// ================= 256x256 8-phase GEMM (m201 template, plain HIP) ==========
// C[M,N] = A[M,K]bf16 @ Bt[N,K]bf16^T. 512 thr (8 waves, 2Mx4N), BK=64,
// 2-tile LDS double-buffer (128 KiB dynamic), st-16-style XOR swizzle,
// counted vmcnt(2) at phases 4/8 only, raw s_barrier (no vmcnt drain),
// setprio(1) around each 16-MFMA cluster.
// MODE 0: +qkv_b, scatter Q(*0.125)/K -> [BH,T,D], V -> [BH,D,T]
// MODE 2: +ff_b1, exact GELU -> bf16 ob0 (stride FFD)
// MODE 3: FF2 split-K: z==0 -> of = acc+bias+resid; z>0 -> bf16 partial pz
#define MM16(AF, BF, MB, NB)                                                   \
  do {                                                                         \
    _Pragma("unroll") for (int m_ = 0; m_ < 4; m_++)                           \
    _Pragma("unroll") for (int n_ = 0; n_ < 2; n_++)                           \
    _Pragma("unroll") for (int k_ = 0; k_ < 2; k_++)                           \
      acc[(MB) + m_][(NB) + n_] = __builtin_amdgcn_mfma_f32_16x16x32_bf16(     \
          AF[m_ * 2 + k_], BF[n_ * 2 + k_], acc[(MB) + m_][(NB) + n_], 0, 0, 0); \
  } while (0)

#define LDA4(DST, MI0, CB)                                                     \
  do {                                                                         \
    const char* ab_ = lds + (CB) * 65536 + aoff;                               \
    _Pragma("unroll") for (int m_ = 0; m_ < 4; m_++) {                         \
      DST[m_ * 2 + 0] = *(const bf16x8*)(ab_ + ((MI0) + m_) * 2048 + xk0);     \
      DST[m_ * 2 + 1] = *(const bf16x8*)(ab_ + ((MI0) + m_) * 2048 + xk1);     \
    }                                                                          \
  } while (0)

#define LDB4(DST, NJ0, CB)                                                     \
  do {                                                                         \
    const char* bb_ = lds + (CB) * 65536 + boff;                               \
    _Pragma("unroll") for (int n_ = 0; n_ < 2; n_++) {                         \
      DST[n_ * 2 + 0] = *(const bf16x8*)(bb_ + ((NJ0) + n_) * 2048 + xk0);     \
      DST[n_ * 2 + 1] = *(const bf16x8*)(bb_ + ((NJ0) + n_) * 2048 + xk1);     \
    }                                                                          \
  } while (0)

#define PH_TAIL(MMBLOCK, DOVM)                                                 \
  __builtin_amdgcn_s_barrier();                                                \
  asm volatile("s_waitcnt lgkmcnt(0)" ::: "memory");                           \
  __builtin_amdgcn_sched_barrier(0);                                           \
  __builtin_amdgcn_s_setprio(1);                                               \
  MMBLOCK;                                                                     \
  __builtin_amdgcn_s_setprio(0);                                               \
  if (DOVM) asm volatile("s_waitcnt vmcnt(2)" ::: "memory");                   \
  __builtin_amdgcn_s_barrier();

template <int MODE>
__global__ void __launch_bounds__(512, 2)
gemm8p(const u16* __restrict__ Aa, const u16* __restrict__ Bt,
       const float* __restrict__ bias, const float* __restrict__ resid,
       u16* __restrict__ ob0, u16* __restrict__ ob1, u16* __restrict__ ob2,
       float* __restrict__ of, u16* __restrict__ p1, u16* __restrict__ p2,
       u16* __restrict__ p3, int N, int K, int lda, int ldb) {
  extern __shared__ char lds[];
  const int tid = threadIdx.x, lane = tid & 63, w = tid >> 6;
  const int wr = w >> 2, wc = w & 3;  // wave tile 128x64 at (wr*128, wc*64)
  const int l15 = lane & 15, hi4 = lane >> 4, l7 = lane & 7, l8 = lane >> 3;
  const int m0 = blockIdx.y * 256, n0 = blockIdx.x * 256;
  const int z = blockIdx.z;
  const size_t koff = (size_t)z * K;
  const int NT = K >> 6;  // 64-wide K tiles

  // ds_read bases: row*128B, x = (kc*64 + hi4*16) ^ ((row&7)<<4); row&7==l7
  const int aoff = wr * 16384 + l15 * 128;
  const int boff = 32768 + (wc >> 1) * 16384 + ((wc & 1) * 64 + l15) * 128;
  const int xk0 = (hi4 << 4) ^ (l7 << 4);
  const int xk1 = xk0 ^ 64;

  // staging: wave w stages rows [w*16, w*16+16) of each 128-row half;
  // pre-swizzled global source so linear gload_lds dest yields swizzled LDS
  const int swzel = (l7 ^ l8) << 3;  // elems
  const u16* Abase = Aa + (size_t)(m0 + w * 16 + l8) * lda + koff + swzel;
  const u16* Bbase = Bt + (size_t)(n0 + w * 16 + l8) * ldb + koff + swzel;
  char* ldsw = lds + w * 2048 + lane * 16;

  f32x4 acc[8][4];
#pragma unroll
  for (int i = 0; i < 8; i++)
#pragma unroll
    for (int j = 0; j < 4; j++) acc[i][j] = (f32x4){0.f, 0.f, 0.f, 0.f};

  auto STAGE = [&](int t, int hid) {
    int tc = t < NT ? t : NT - 1;  // clamp: dummy refetch, target buf is dead
    int H = hid & 1;
    const u16* g;
    char* d;
    int ld;
    if (hid < 2) {
      g = Abase + (size_t)H * 128 * lda + tc * 64;
      d = ldsw + (t & 1) * 65536 + H * 16384;
      ld = lda;
    } else {
      g = Bbase + (size_t)H * 128 * ldb + tc * 64;
      d = ldsw + (t & 1) * 65536 + 32768 + H * 16384;
      ld = ldb;
    }
    gload_lds16(g, d);
    gload_lds16(g + (size_t)8 * ld, d + 1024);
  };

  // prologue: tile0 all 4 halves + tile1 half0, allow tile1.h0 in flight
  STAGE(0, 0); STAGE(0, 1); STAGE(0, 2); STAGE(0, 3);
  STAGE(1, 0);
  asm volatile("s_waitcnt vmcnt(2)" ::: "memory");
  __builtin_amdgcn_s_barrier();

  bf16x8 a[8], b01[4], b23[4];
  const int NP = NT >> 1;
  for (int i = 0; i < NP; i++) {
    const int T = 2 * i;
    // ph1: tile T (buf0) quadrant m0-3 x n0-1
    LDA4(a, 0, 0);
    LDB4(b01, 0, 0);
    STAGE(T + 1, 1);
    PH_TAIL(MM16(a, b01, 0, 0), 0)
    // ph2: m0-3 x n2-3
    LDB4(b23, 2, 0);
    STAGE(T + 1, 2);
    PH_TAIL(MM16(a, b23, 0, 2), 0)
    // ph3: m4-7 x n0-1
    LDA4(a, 4, 0);
    STAGE(T + 1, 3);
    PH_TAIL(MM16(a, b01, 4, 0), 0)
    // ph4: m4-7 x n2-3 ; wait for tile T+1 before ph5 reads buf1
    STAGE(T + 2, 0);
    PH_TAIL(MM16(a, b23, 4, 2), 1)
    // ph5: tile T+1 (buf1) m0-3 x n0-1
    LDA4(a, 0, 1);
    LDB4(b01, 0, 1);
    STAGE(T + 2, 1);
    PH_TAIL(MM16(a, b01, 0, 0), 0)
    // ph6
    LDB4(b23, 2, 1);
    STAGE(T + 2, 2);
    PH_TAIL(MM16(a, b23, 0, 2), 0)
    // ph7
    LDA4(a, 4, 1);
    STAGE(T + 2, 3);
    PH_TAIL(MM16(a, b01, 4, 0), 0)
    // ph8 ; wait for tile T+2 before next-iter ph1 reads buf0
    STAGE(T + 3, 0);
    PH_TAIL(MM16(a, b23, 4, 2), 1)
  }

  // -------- epilogue --------
#pragma unroll
  for (int mi = 0; mi < 8; mi++) {
#pragma unroll
    for (int nj = 0; nj < 4; nj++) {
      int mb = m0 + wr * 128 + mi * 16 + hi4 * 4;
      int n = n0 + wc * 64 + nj * 16 + l15;
      float v4[4];
      float bv = (MODE == 3) ? 0.f : bias[n];
#pragma unroll
      for (int r = 0; r < 4; r++) v4[r] = acc[mi][nj][r] + bv;
      if (MODE == 0) {
        int b_ = mb >> 11;
        int t = mb & 2047;
        int s = n >> 10;
        int hd = n & 1023;
        int h_ = hd >> 6;
        int d = hd & 63;
        size_t bh = (size_t)b_ * HEADS + h_;
        if (s == 0) {
#pragma unroll
          for (int r = 0; r < 4; r++)
            ob0[(bh * TT + (t + r)) * HD + d] = f2bf(v4[r] * 0.125f);
        } else if (s == 1) {
#pragma unroll
          for (int r = 0; r < 4; r++)
            ob1[(bh * TT + (t + r)) * HD + d] = f2bf(v4[r]);
        } else {
          us4 pk;
#pragma unroll
          for (int r = 0; r < 4; r++) pk[r] = f2bf(v4[r]);
          *(us4*)&ob2[(bh * HD + d) * TT + t] = pk;
        }
      } else if (MODE == 2) {  // exact GELU
#pragma unroll
        for (int r = 0; r < 4; r++)
          ob0[(size_t)(mb + r) * FFD + n] =
              f2bf(0.5f * v4[r] * (1.f + erff(v4[r] * 0.70710678118f)));
      } else {  // MODE 3
        if (z == 0) {
          float bz = bias[n];
#pragma unroll
          for (int r = 0; r < 4; r++) {
            size_t idx = (size_t)(mb + r) * E + n;
            of[idx] = v4[r] + bz + resid[idx];
          }
        } else {
          u16* pz = (z == 1) ? p1 : ((z == 2) ? p2 : p3);
#pragma unroll
          for (int r = 0; r < 4; r++) pz[(size_t)(mb + r) * N + n] = f2bf(v4[r]);
        }
      }
    }
  }
}

// ------------- old 128x128 GEMM, kept for proj (+out_b +resid -> fp32) -----
__global__ void __launch_bounds__(256) gemm128_resid(const u16* __restrict__ Aa,
                                                     const u16* __restrict__ Bt,
                                                     const float* __restrict__ bias,
                                                     const float* __restrict__ resid,
                                                     float* __restrict__ of,
                                                     int N, int K) {
  __shared__ __align__(16) u16 As[128 * 32];
  __shared__ __align__(16) u16 Bs[128 * 32];
  int n0 = blockIdx.x * 128, m0 = blockIdx.y * 128;
  int tid = threadIdx.x, lane = tid & 63;
  int wave = tid >> 6, wr = wave >> 1, wc = wave & 1;

  f32x4 acc[4][4];
#pragma unroll
  for (int i = 0; i < 4; i++)
#pragma unroll
    for (int j = 0; j < 4; j++) acc[i][j] = (f32x4){0.f, 0.f, 0.f, 0.f};

  int c0 = tid, c1 = tid + 256;
  const u16* Ap0 = Aa + (size_t)(m0 + (c0 >> 2)) * K + (c0 & 3) * 8;
  const u16* Ap1 = Aa + (size_t)(m0 + (c1 >> 2)) * K + (c1 & 3) * 8;
  const u16* Bp0 = Bt + (size_t)(n0 + (c0 >> 2)) * K + (c0 & 3) * 8;
  const u16* Bp1 = Bt + (size_t)(n0 + (c1 >> 2)) * K + (c1 & 3) * 8;
  u16* la0 = As + c0 * 8;
  u16* la1 = As + c1 * 8;
  u16* lb0 = Bs + c0 * 8;
  u16* lb1 = Bs + c1 * 8;

  for (int k0 = 0; k0 < K; k0 += 32) {
    gload_lds16(Ap0 + k0, la0);
    gload_lds16(Ap1 + k0, la1);
    gload_lds16(Bp0 + k0, lb0);
    gload_lds16(Bp1 + k0, lb1);
    __syncthreads();
    bf16x8 af[4], bfr[4];
#pragma unroll
    for (int i = 0; i < 4; i++)
      af[i] = *(const bf16x8*)&As[(wr * 64 + i * 16 + (lane & 15)) * 32 + (lane >> 4) * 8];
#pragma unroll
    for (int j = 0; j < 4; j++)
      bfr[j] = *(const bf16x8*)&Bs[(wc * 64 + j * 16 + (lane & 15)) * 32 + (lane >> 4) * 8];
#pragma unroll
    for (int i = 0; i < 4; i++)
#pragma unroll
      for (int j = 0; j < 4; j++)
        acc[i][j] = __builtin_amdgcn_mfma_f32_16x16x32_bf16(af[i], bfr[j], acc[i][j], 0, 0, 0);
    __syncthreads();
  }

#pragma unroll
  for (int i = 0; i < 4; i++) {
#pragma unroll
    for (int j = 0; j < 4; j++) {
      int mb = m0 + wr * 64 + i * 16 + ((lane >> 4) << 2);
      int n = n0 + wc * 64 + j * 16 + (lane & 15);
      float bv = bias[n];
#pragma unroll
      for (int r = 0; r < 4; r++) {
        size_t idx = (size_t)(mb + r) * E + n;
        of[idx] = acc[i][j][r] + bv + resid[idx];
      }
    }
  }
}

// ------------- FF2 split-K reduce: out += p1 + p2 + p3 -------------
__global__ void __launch_bounds__(256) ff2_reduce(const u16* __restrict__ p1,
                                                  const u16* __restrict__ p2,
                                                  const u16* __restrict__ p3,
                                                  float* __restrict__ out) {
  size_t i = ((size_t)blockIdx.x * 256 + threadIdx.x) * 4;
  us4 a = *(const us4*)(p1 + i);
  us4 b = *(const us4*)(p2 + i);
  us4 c = *(const us4*)(p3 + i);
  float4 o = *(const float4*)(out + i);
  o.x += bf2f(a.x) + bf2f(b.x) + bf2f(c.x);
  o.y += bf2f(a.y) + bf2f(b.y) + bf2f(c.y);
  o.z += bf2f(a.z) + bf2f(b.z) + bf2f(c.z);
  o.w += bf2f(a.w) + bf2f(b.w) + bf2f(c.w);
  *(float4*)(out + i) = o;
}

// ------------- Flash attention, swapped-operand 32x32 structure -------------
__global__ void __launch_bounds__(64) attn_kernel(const u16* __restrict__ Qb,
                                                  const u16* __restrict__ Kb,
                                                  const u16* __restrict__ Vt,
                                                  u16* __restrict__ O) {
  int bid = blockIdx.x;
  int bh = bid & 31;
  int q0 = (bid >> 5) << 5;
  int b = bh >> 4, h = bh & 15;
  int lane = threadIdx.x;
  int lq = lane & 31, hi = lane >> 5;

  const u16* Qp = Qb + ((size_t)bh * TT + q0 + lq) * HD + hi * 8;
  bf16x8 qf[4];
#pragma unroll
  for (int c = 0; c < 4; c++) qf[c] = *(const bf16x8*)(Qp + c * 16);

  const u16* Kbase = Kb + ((size_t)bh * TT + lq) * HD + hi * 8;
  const u16* Vbase = Vt + ((size_t)bh * HD + lq) * TT + hi * 8;

  f32x16 o0, o1;
#pragma unroll
  for (int r = 0; r < 16; r++) { o0[r] = 0.f; o1[r] = 0.f; }
  float m_run = -1e30f, l_run = 0.f;

  for (int kv0 = 0; kv0 < TT; kv0 += 32) {
    const u16* Kp = Kbase + (size_t)kv0 * HD;
    bf16x8 kf[4];
#pragma unroll
    for (int c = 0; c < 4; c++) kf[c] = *(const bf16x8*)(Kp + c * 16);

    f32x16 s;
#pragma unroll
    for (int r = 0; r < 16; r++) s[r] = 0.f;
#pragma unroll
    for (int c = 0; c < 4; c++)
      s = __builtin_amdgcn_mfma_f32_32x32x16_bf16(kf[c], qf[c], s, 0, 0, 0);

    float mx = s[0];
#pragma unroll
    for (int r = 1; r < 16; r++) mx = fmaxf(mx, s[r]);
    mx = fmaxf(mx, __shfl_xor(mx, 32));

    if (__any(mx > m_run + 8.f)) {  // T13 defer-max
      float mn = fmaxf(m_run, mx);
      float al = __expf(m_run - mn);
#pragma unroll
      for (int r = 0; r < 16; r++) { o0[r] *= al; o1[r] *= al; }
      l_run *= al;
      m_run = mn;
    }

    float p[16], ps = 0.f;
#pragma unroll
    for (int r = 0; r < 16; r++) {
      p[r] = __expf(s[r] - m_run);
      ps += p[r];
    }
    l_run += ps + __shfl_xor(ps, 32);

    u32 wv[8];
#pragma unroll
    for (int c = 0; c < 2; c++) {
      u32 qA = cvtpk(p[c * 8 + 0], p[c * 8 + 1]);
      u32 qB = cvtpk(p[c * 8 + 2], p[c * 8 + 3]);
      u32 qC = cvtpk(p[c * 8 + 4], p[c * 8 + 5]);
      u32 qD = cvtpk(p[c * 8 + 6], p[c * 8 + 7]);
      u32 As_ = __shfl_xor(qA, 32), Bs_ = __shfl_xor(qB, 32);
      u32 Cs_ = __shfl_xor(qC, 32), Ds_ = __shfl_xor(qD, 32);
      wv[c * 4 + 0] = hi ? Cs_ : qA;
      wv[c * 4 + 1] = hi ? Ds_ : qB;
      wv[c * 4 + 2] = hi ? qC : As_;
      wv[c * 4 + 3] = hi ? qD : Bs_;
    }
    u32x4 t0 = {wv[0], wv[1], wv[2], wv[3]};
    u32x4 t1 = {wv[4], wv[5], wv[6], wv[7]};
    bf16x8 pf0 = __builtin_bit_cast(bf16x8, t0);
    bf16x8 pf1 = __builtin_bit_cast(bf16x8, t1);

    const u16* Vp = Vbase + kv0;
    bf16x8 v00 = *(const bf16x8*)(Vp);
    bf16x8 v01 = *(const bf16x8*)(Vp + 16);
    bf16x8 v10 = *(const bf16x8*)(Vp + (size_t)32 * TT);
    bf16x8 v11 = *(const bf16x8*)(Vp + (size_t)32 * TT + 16);
    o0 = __builtin_amdgcn_mfma_f32_32x32x16_bf16(v00, pf0, o0, 0, 0, 0);
    o0 = __builtin_amdgcn_mfma_f32_32x32x16_bf16(v01, pf1, o0, 0, 0, 0);
    o1 = __builtin_amdgcn_mfma_f32_32x32x16_bf16(v10, pf0, o1, 0, 0, 0);
    o1 = __builtin_amdgcn_mfma_f32_32x32x16_bf16(v11, pf1, o1, 0, 0, 0);
  }

  float rl = 1.f / l_run;
  const size_t orow = ((size_t)b * TT + q0 + lq) * E + h * HD;
#pragma unroll
  for (int r = 0; r < 16; r++) {
    int d = (r & 3) + ((r >> 2) << 3) + (hi << 2);
    O[orow + d] = f2bf(o0[r] * rl);
    O[orow + 32 + d] = f2bf(o1[r] * rl);
  }
}

extern "C" void kernel_launch(void* const* d_in, const int* in_sizes, int n_in,
                              void* d_out, int out_size, void* d_ws, size_t ws_size,
                              hipStream_t stream) {
  (void)in_sizes; (void)n_in; (void)out_size; (void)ws_size;
  const float* x = (const float*)d_in[0];
  const float* qkv_w = (const float*)d_in[1];
  const float* qkv_b = (const float*)d_in[2];
  const float* out_w = (const float*)d_in[3];
  const float* out_b = (const float*)d_in[4];
  const float* ff_w1 = (const float*)d_in[5];
  const float* ff_b1 = (const float*)d_in[6];
  const float* ff_w2 = (const float*)d_in[7];
  const float* ff_b2 = (const float*)d_in[8];
  const float* ln1_g = (const float*)d_in[9];
  const float* ln1_b = (const float*)d_in[10];
  const float* ln2_g = (const float*)d_in[11];
  const float* ln2_b = (const float*)d_in[12];

  char* ws = (char*)d_ws;
  u16* qkvwt = (u16*)(ws + 0);           // [0,6M)   dead after QKV gemm
  u16* outwt = (u16*)(ws + 6291456);     // [6,8M)   dead after proj
  u16* ffw1t = (u16*)(ws + 8388608);     // [8,16M)  dead after FF1
  u16* ffw2t = (u16*)(ws + 16777216);    // [16,24M) live through FF2
  u16* ln_out = (u16*)(ws + 25165824);   // [24,32M) dead after FF1
  float* x1 = (float*)(ws + 33554432);   // [32,48M) live (FF2 resid)
  u16* qb = (u16*)(ws + 50331648);       // [48,56M)
  u16* kb = (u16*)(ws + 58720256);       // [56,64M)
  u16* vt = (u16*)(ws + 67108864);       // [64,72M)
  u16* attn_o = (u16*)(ws + 75497472);   // [72,80M) dead after proj
  u16* hbuf = (u16*)(ws + 50331648);     // [48,80M) FF1 out, live through FF2
  u16* pp1 = (u16*)(ws + 0);             // [0,8M)   FF2 partial z=1
  u16* pp2 = (u16*)(ws + 8388608);       // [8,16M)  FF2 partial z=2
  u16* pp3 = (u16*)(ws + 25165824);      // [24,32M) FF2 partial z=3

  hipFuncSetAttribute((const void*)gemm8p<0>,
                      hipFuncAttributeMaxDynamicSharedMemorySize, 131072);
  hipFuncSetAttribute((const void*)gemm8p<2>,
                      hipFuncAttributeMaxDynamicSharedMemorySize, 131072);
  hipFuncSetAttribute((const void*)gemm8p<3>,
                      hipFuncAttributeMaxDynamicSharedMemorySize, 131072);

  dim3 tb(32, 8);
  transpose_bf16<<<dim3(3072 / 32, 1024 / 32), tb, 0, stream>>>(qkv_w, qkvwt, 1024, 3072);
  transpose_bf16<<<dim3(1024 / 32, 1024 / 32), tb, 0, stream>>>(out_w, outwt, 1024, 1024);
  transpose_bf16<<<dim3(4096 / 32, 1024 / 32), tb, 0, stream>>>(ff_w1, ffw1t, 1024, 4096);
  transpose_bf16<<<dim3(1024 / 32, 4096 / 32), tb, 0, stream>>>(ff_w2, ffw2t, 4096, 1024);

  ln_kernel<<<MMDIM, 256, 0, stream>>>(x, ln1_g, ln1_b, ln_out);
  gemm8p<0><<<dim3(12, 16, 1), 512, 131072, stream>>>(
      ln_out, qkvwt, qkv_b, nullptr, qb, kb, vt, nullptr, nullptr, nullptr, nullptr,
      3072, 1024, 1024, 1024);
  attn_kernel<<<dim3((TT / 32) * 32), 64, 0, stream>>>(qb, kb, vt, attn_o);
  gemm128_resid<<<dim3(1024 / 128, MMDIM / 128), 256, 0, stream>>>(
      attn_o, outwt, out_b, x, x1, 1024, 1024);
  ln_kernel<<<MMDIM, 256, 0, stream>>>(x1, ln2_g, ln2_b, ln_out);
  gemm8p<2><<<dim3(16, 16, 1), 512, 131072, stream>>>(
      ln_out, ffw1t, ff_b1, nullptr, hbuf, nullptr, nullptr, nullptr, nullptr, nullptr,
      nullptr, 4096, 1024, 1024, 1024);
  gemm8p<3><<<dim3(4, 16, 4), 512, 131072, stream>>>(
      hbuf, ffw2t, ff_b2, x1, nullptr, nullptr, nullptr, (float*)d_out, pp1, pp2, pp3,
      1024, 1024, 4096, 4096);
  ff2_reduce<<<(size_t)MMDIM * E / 1024, 256, 0, stream>>>(pp1, pp2, pp3, (float*)d_out);
}

// Round 4
// 328.902 us; speedup vs baseline: 1.2367x; 1.2367x over previous
//
#include <hip/hip_runtime.h>

#define E     1024
#define HEADS 16
#define HD    64
#define FFD   4096
#define TT    2048
#define MMDIM 4096   // B*T

typedef __bf16 bf16x8 __attribute__((ext_vector_type(8)));
typedef float f32x4 __attribute__((ext_vector_type(4)));
typedef float f32x16 __attribute__((ext_vector_type(16)));
typedef unsigned short u16;
typedef unsigned u32;
typedef u16 ushort8 __attribute__((ext_vector_type(8)));
typedef u16 us4 __attribute__((ext_vector_type(4)));
typedef u32 u32x4 __attribute__((ext_vector_type(4)));

__device__ __forceinline__ u16 f2bf(float f) {
  unsigned u = __float_as_uint(f);
  u = (u + 0x7fffu + ((u >> 16) & 1u)) >> 16;
  return (u16)u;
}
__device__ __forceinline__ float bf2f(u16 u) {
  return __uint_as_float(((unsigned)u) << 16);
}
__device__ __forceinline__ u32 cvtpk(float a, float b) {
  u32 r;
  asm("v_cvt_pk_bf16_f32 %0, %1, %2" : "=v"(r) : "v"(a), "v"(b));
  return r;
}

__device__ __forceinline__ void gload_lds16(const void* g, void* l) {
  __builtin_amdgcn_global_load_lds((__attribute__((address_space(1))) void*)g,
                                   (__attribute__((address_space(3))) void*)l,
                                   16, 0, 0);
}

// ---------------- LayerNorm: fp32 in -> bf16 out ----------------
__global__ void __launch_bounds__(256) ln_kernel(const float* __restrict__ x,
                                                 const float* __restrict__ g,
                                                 const float* __restrict__ b,
                                                 u16* __restrict__ out) {
  int row = blockIdx.x;
  int t = threadIdx.x;
  const float4 v = reinterpret_cast<const float4*>(x + (size_t)row * E)[t];
  float s = v.x + v.y + v.z + v.w;
  float s2 = v.x * v.x + v.y * v.y + v.z * v.z + v.w * v.w;
#pragma unroll
  for (int m = 1; m < 64; m <<= 1) {
    s += __shfl_xor(s, m);
    s2 += __shfl_xor(s2, m);
  }
  __shared__ float red[8];
  int wave = t >> 6, lane = t & 63;
  if (lane == 0) { red[wave] = s; red[wave + 4] = s2; }
  __syncthreads();
  s = red[0] + red[1] + red[2] + red[3];
  s2 = red[4] + red[5] + red[6] + red[7];
  float mean = s * (1.f / E);
  float var = s2 * (1.f / E) - mean * mean;
  float inv = rsqrtf(var + 1e-5f);
  const float4 gv = reinterpret_cast<const float4*>(g)[t];
  const float4 bv = reinterpret_cast<const float4*>(b)[t];
  us4 pk;
  pk.x = f2bf((v.x - mean) * inv * gv.x + bv.x);
  pk.y = f2bf((v.y - mean) * inv * gv.y + bv.y);
  pk.z = f2bf((v.z - mean) * inv * gv.z + bv.z);
  pk.w = f2bf((v.w - mean) * inv * gv.w + bv.w);
  *(us4*)(out + (size_t)row * E + t * 4) = pk;
}

// ------------- Transpose+convert: W[K,N] fp32 -> Wt[N,K] bf16 -------------
__global__ void __launch_bounds__(256) transpose_bf16(const float* __restrict__ in,
                                                      u16* __restrict__ out,
                                                      int K, int N) {
  __shared__ float tile[32][33];
  int k0 = blockIdx.y * 32, n0 = blockIdx.x * 32;
  int tx = threadIdx.x, ty = threadIdx.y;  // block (32,8)
#pragma unroll
  for (int i = ty; i < 32; i += 8)
    tile[i][tx] = in[(size_t)(k0 + i) * N + n0 + tx];
  __syncthreads();
#pragma unroll
  for (int i = ty; i < 32; i += 8)
    out[(size_t)(n0 + i) * K + k0 + tx] = f2bf(tile[tx][i]);
}

// ========== min-2-phase prefetching GEMM (T3 minimum recipe) ==========
// C[M,N] = A[M,K]bf16 @ Bt[N,K]bf16^T. 128x128 tile, BK=64, 4 waves (2x2),
// explicit LDS double-buffer (2x32 KiB): STAGE(t+1) issued BEFORE compute(t),
// single vmcnt(0)+s_barrier per K-step at the END -> load latency hides
// under ds_read+MFMA of the current tile. T2 XOR-swizzle both sides.
// MODE 0: +qkv_b, scatter Q(*0.125)/K -> [BH,T,D], V -> [BH,D,T]
// MODE 1: +out_b +resid -> fp32 of
// MODE 2: +ff_b1, exact GELU -> bf16 ob0 (stride FFD)
// MODE 4: split-K partial (no bias) -> bf16 ob0 at z*pstride
template <int MODE>
__global__ void __launch_bounds__(256) gemm2p(const u16* __restrict__ Aa,
                                              const u16* __restrict__ Bt,
                                              const float* __restrict__ bias,
                                              const float* __restrict__ resid,
                                              u16* __restrict__ ob0,
                                              u16* __restrict__ ob1,
                                              u16* __restrict__ ob2,
                                              float* __restrict__ of,
                                              int N, int K, int lda, int ldb,
                                              int pstride) {
  __shared__ __align__(16) u16 As[2][128 * 64];
  __shared__ __align__(16) u16 Bs[2][128 * 64];
  const int n0 = blockIdx.x * 128, m0 = blockIdx.y * 128;
  const int tid = threadIdx.x, lane = tid & 63;
  const int wave = tid >> 6, wr = wave >> 1, wc = wave & 1;
  const int l15 = lane & 15, hi4 = lane >> 4, l7 = lane & 7;
  const size_t koff = (size_t)blockIdx.z * K;
  const int nt = K >> 6;

  f32x4 acc[4][4];
#pragma unroll
  for (int i = 0; i < 4; i++)
#pragma unroll
    for (int j = 0; j < 4; j++) acc[i][j] = (f32x4){0.f, 0.f, 0.f, 0.f};

  // staging pointers: chunk c = tid + r*256 covers 128 rows x 8 chunks of
  // 8 elems; global col chunk pre-swizzled by row&7 (T2, both-sides rule 21)
  const u16* ApR[4];
  const u16* BpR[4];
#pragma unroll
  for (int r = 0; r < 4; r++) {
    int c = tid + r * 256;
    int row = c >> 3;
    int col = ((c & 7) ^ (row & 7)) * 8;
    ApR[r] = Aa + (size_t)(m0 + row) * lda + koff + col;
    BpR[r] = Bt + (size_t)(n0 + row) * ldb + koff + col;
  }

  // ds_read swizzled k-offsets (bytes): kb = ks*64 + hi4*16, swz ^= l7<<4
  const int xk0 = (hi4 << 4) ^ (l7 << 4);
  const int xk1 = (64 + (hi4 << 4)) ^ (l7 << 4);

#define STAGE2P(T, BUF)                                                        \
  do {                                                                         \
    int k0_ = (T) << 6;                                                        \
    _Pragma("unroll") for (int r_ = 0; r_ < 4; r_++) {                         \
      int c_ = tid + r_ * 256;                                                 \
      gload_lds16(ApR[r_] + k0_, &As[BUF][c_ * 8]);                            \
      gload_lds16(BpR[r_] + k0_, &Bs[BUF][c_ * 8]);                            \
    }                                                                          \
  } while (0)

  STAGE2P(0, 0);
  asm volatile("s_waitcnt vmcnt(0)" ::: "memory");
  __builtin_amdgcn_s_barrier();
  __builtin_amdgcn_sched_barrier(0);

  for (int t = 0; t < nt; ++t) {
    const int cur = t & 1;
    if (t + 1 < nt) {
      if (cur == 0) STAGE2P(t + 1, 1);
      else          STAGE2P(t + 1, 0);
    }
    // ds_read current tile fragments (swizzled)
    const char* ab = (const char*)&As[0][0] + cur * 16384;
    const char* bb = (const char*)&Bs[0][0] + cur * 16384;
    bf16x8 a0[4], a1[4], b0[4], b1[4];
#pragma unroll
    for (int i = 0; i < 4; i++) {
      int rowb = (wr * 64 + i * 16 + l15) * 128;
      a0[i] = *(const bf16x8*)(ab + rowb + xk0);
      a1[i] = *(const bf16x8*)(ab + rowb + xk1);
    }
#pragma unroll
    for (int j = 0; j < 4; j++) {
      int rowb = (wc * 64 + j * 16 + l15) * 128;
      b0[j] = *(const bf16x8*)(bb + rowb + xk0);
      b1[j] = *(const bf16x8*)(bb + rowb + xk1);
    }
    asm volatile("s_waitcnt lgkmcnt(0)" ::: "memory");
    __builtin_amdgcn_sched_barrier(0);
    __builtin_amdgcn_s_setprio(1);
#pragma unroll
    for (int i = 0; i < 4; i++)
#pragma unroll
      for (int j = 0; j < 4; j++) {
        acc[i][j] = __builtin_amdgcn_mfma_f32_16x16x32_bf16(a0[i], b0[j], acc[i][j], 0, 0, 0);
        acc[i][j] = __builtin_amdgcn_mfma_f32_16x16x32_bf16(a1[i], b1[j], acc[i][j], 0, 0, 0);
      }
    __builtin_amdgcn_s_setprio(0);
    // single drain per K-step: next-tile loads (issued ~1 step ago) + all
    // waves' ds_reads of cur done -> safe to overwrite cur next iteration
    asm volatile("s_waitcnt vmcnt(0)" ::: "memory");
    __builtin_amdgcn_s_barrier();
    __builtin_amdgcn_sched_barrier(0);
  }
#undef STAGE2P

  // -------- epilogue --------
#pragma unroll
  for (int i = 0; i < 4; i++) {
#pragma unroll
    for (int j = 0; j < 4; j++) {
      int mb = m0 + wr * 64 + i * 16 + (hi4 << 2);
      int n = n0 + wc * 64 + j * 16 + l15;
      float bv = (MODE == 4) ? 0.f : bias[n];
      float v4[4];
#pragma unroll
      for (int r = 0; r < 4; r++) v4[r] = acc[i][j][r] + bv;
      if (MODE == 0) {
        int b_ = mb >> 11;
        int t = mb & 2047;
        int s = n >> 10;
        int hd = n & 1023;
        int h_ = hd >> 6;
        int d = hd & 63;
        size_t bh = (size_t)b_ * HEADS + h_;
        if (s == 0) {
#pragma unroll
          for (int r = 0; r < 4; r++)
            ob0[(bh * TT + (t + r)) * HD + d] = f2bf(v4[r] * 0.125f);
        } else if (s == 1) {
#pragma unroll
          for (int r = 0; r < 4; r++)
            ob1[(bh * TT + (t + r)) * HD + d] = f2bf(v4[r]);
        } else {
          us4 pk;
#pragma unroll
          for (int r = 0; r < 4; r++) pk[r] = f2bf(v4[r]);
          *(us4*)&ob2[(bh * HD + d) * TT + t] = pk;
        }
      } else if (MODE == 1) {
#pragma unroll
        for (int r = 0; r < 4; r++) {
          size_t idx = (size_t)(mb + r) * E + n;
          of[idx] = v4[r] + resid[idx];
        }
      } else if (MODE == 2) {  // exact GELU
#pragma unroll
        for (int r = 0; r < 4; r++)
          ob0[(size_t)(mb + r) * FFD + n] =
              f2bf(0.5f * v4[r] * (1.f + erff(v4[r] * 0.70710678118f)));
      } else {  // MODE 4: bf16 partial
        size_t zoff = (size_t)blockIdx.z * pstride;
#pragma unroll
        for (int r = 0; r < 4; r++)
          ob0[zoff + (size_t)(mb + r) * N + n] = f2bf(v4[r]);
      }
    }
  }
}

// ------------- FF2 split-K reduce: out = resid + bias + p0 + p1 -------------
__global__ void __launch_bounds__(256) ff2_reduce(const u16* __restrict__ p0,
                                                  const u16* __restrict__ p1,
                                                  const float* __restrict__ bias,
                                                  const float* __restrict__ resid,
                                                  float* __restrict__ out) {
  size_t i = ((size_t)blockIdx.x * 256 + threadIdx.x) * 4;
  int n = (int)(i & (E - 1));
  us4 a = *(const us4*)(p0 + i);
  us4 c = *(const us4*)(p1 + i);
  float4 r = *(const float4*)(resid + i);
  const float4 bs = *(const float4*)(bias + n);
  float4 o;
  o.x = r.x + bs.x + bf2f(a.x) + bf2f(c.x);
  o.y = r.y + bs.y + bf2f(a.y) + bf2f(c.y);
  o.z = r.z + bs.z + bf2f(a.z) + bf2f(c.z);
  o.w = r.w + bs.w + bf2f(a.w) + bf2f(c.w);
  *(float4*)(out + i) = o;
}

// ------------- Flash attention, swapped-operand 32x32 structure -------------
__global__ void __launch_bounds__(64) attn_kernel(const u16* __restrict__ Qb,
                                                  const u16* __restrict__ Kb,
                                                  const u16* __restrict__ Vt,
                                                  u16* __restrict__ O) {
  int bid = blockIdx.x;
  int bh = bid & 31;
  int q0 = (bid >> 5) << 5;
  int b = bh >> 4, h = bh & 15;
  int lane = threadIdx.x;
  int lq = lane & 31, hi = lane >> 5;

  const u16* Qp = Qb + ((size_t)bh * TT + q0 + lq) * HD + hi * 8;
  bf16x8 qf[4];
#pragma unroll
  for (int c = 0; c < 4; c++) qf[c] = *(const bf16x8*)(Qp + c * 16);

  const u16* Kbase = Kb + ((size_t)bh * TT + lq) * HD + hi * 8;
  const u16* Vbase = Vt + ((size_t)bh * HD + lq) * TT + hi * 8;

  f32x16 o0, o1;
#pragma unroll
  for (int r = 0; r < 16; r++) { o0[r] = 0.f; o1[r] = 0.f; }
  float m_run = -1e30f, l_run = 0.f;

  for (int kv0 = 0; kv0 < TT; kv0 += 32) {
    const u16* Kp = Kbase + (size_t)kv0 * HD;
    bf16x8 kf[4];
#pragma unroll
    for (int c = 0; c < 4; c++) kf[c] = *(const bf16x8*)(Kp + c * 16);

    f32x16 s;
#pragma unroll
    for (int r = 0; r < 16; r++) s[r] = 0.f;
#pragma unroll
    for (int c = 0; c < 4; c++)
      s = __builtin_amdgcn_mfma_f32_32x32x16_bf16(kf[c], qf[c], s, 0, 0, 0);

    float mx = s[0];
#pragma unroll
    for (int r = 1; r < 16; r++) mx = fmaxf(mx, s[r]);
    mx = fmaxf(mx, __shfl_xor(mx, 32));

    if (__any(mx > m_run + 8.f)) {  // T13 defer-max
      float mn = fmaxf(m_run, mx);
      float al = __expf(m_run - mn);
#pragma unroll
      for (int r = 0; r < 16; r++) { o0[r] *= al; o1[r] *= al; }
      l_run *= al;
      m_run = mn;
    }

    float p[16], ps = 0.f;
#pragma unroll
    for (int r = 0; r < 16; r++) {
      p[r] = __expf(s[r] - m_run);
      ps += p[r];
    }
    l_run += ps + __shfl_xor(ps, 32);

    u32 wv[8];
#pragma unroll
    for (int c = 0; c < 2; c++) {
      u32 qA = cvtpk(p[c * 8 + 0], p[c * 8 + 1]);
      u32 qB = cvtpk(p[c * 8 + 2], p[c * 8 + 3]);
      u32 qC = cvtpk(p[c * 8 + 4], p[c * 8 + 5]);
      u32 qD = cvtpk(p[c * 8 + 6], p[c * 8 + 7]);
      u32 As_ = __shfl_xor(qA, 32), Bs_ = __shfl_xor(qB, 32);
      u32 Cs_ = __shfl_xor(qC, 32), Ds_ = __shfl_xor(qD, 32);
      wv[c * 4 + 0] = hi ? Cs_ : qA;
      wv[c * 4 + 1] = hi ? Ds_ : qB;
      wv[c * 4 + 2] = hi ? qC : As_;
      wv[c * 4 + 3] = hi ? qD : Bs_;
    }
    u32x4 t0 = {wv[0], wv[1], wv[2], wv[3]};
    u32x4 t1 = {wv[4], wv[5], wv[6], wv[7]};
    bf16x8 pf0 = __builtin_bit_cast(bf16x8, t0);
    bf16x8 pf1 = __builtin_bit_cast(bf16x8, t1);

    const u16* Vp = Vbase + kv0;
    bf16x8 v00 = *(const bf16x8*)(Vp);
    bf16x8 v01 = *(const bf16x8*)(Vp + 16);
    bf16x8 v10 = *(const bf16x8*)(Vp + (size_t)32 * TT);
    bf16x8 v11 = *(const bf16x8*)(Vp + (size_t)32 * TT + 16);
    o0 = __builtin_amdgcn_mfma_f32_32x32x16_bf16(v00, pf0, o0, 0, 0, 0);
    o0 = __builtin_amdgcn_mfma_f32_32x32x16_bf16(v01, pf1, o0, 0, 0, 0);
    o1 = __builtin_amdgcn_mfma_f32_32x32x16_bf16(v10, pf0, o1, 0, 0, 0);
    o1 = __builtin_amdgcn_mfma_f32_32x32x16_bf16(v11, pf1, o1, 0, 0, 0);
  }

  float rl = 1.f / l_run;
  const size_t orow = ((size_t)b * TT + q0 + lq) * E + h * HD;
#pragma unroll
  for (int r = 0; r < 16; r++) {
    int d = (r & 3) + ((r >> 2) << 3) + (hi << 2);
    O[orow + d] = f2bf(o0[r] * rl);
    O[orow + 32 + d] = f2bf(o1[r] * rl);
  }
}

extern "C" void kernel_launch(void* const* d_in, const int* in_sizes, int n_in,
                              void* d_out, int out_size, void* d_ws, size_t ws_size,
                              hipStream_t stream) {
  (void)in_sizes; (void)n_in; (void)out_size; (void)ws_size;
  const float* x = (const float*)d_in[0];
  const float* qkv_w = (const float*)d_in[1];
  const float* qkv_b = (const float*)d_in[2];
  const float* out_w = (const float*)d_in[3];
  const float* out_b = (const float*)d_in[4];
  const float* ff_w1 = (const float*)d_in[5];
  const float* ff_b1 = (const float*)d_in[6];
  const float* ff_w2 = (const float*)d_in[7];
  const float* ff_b2 = (const float*)d_in[8];
  const float* ln1_g = (const float*)d_in[9];
  const float* ln1_b = (const float*)d_in[10];
  const float* ln2_g = (const float*)d_in[11];
  const float* ln2_b = (const float*)d_in[12];

  char* ws = (char*)d_ws;
  u16* qkvwt = (u16*)(ws + 0);           // [0,6M)   dead after QKV gemm
  u16* outwt = (u16*)(ws + 6291456);     // [6,8M)   dead after proj
  u16* ffw1t = (u16*)(ws + 8388608);     // [8,16M)  dead after FF1
  u16* ffw2t = (u16*)(ws + 16777216);    // [16,24M) live through FF2
  u16* ln_out = (u16*)(ws + 25165824);   // [24,32M) dead after FF1
  float* x1 = (float*)(ws + 33554432);   // [32,48M) live (FF2 resid)
  u16* qb = (u16*)(ws + 50331648);       // [48,56M)
  u16* kb = (u16*)(ws + 58720256);       // [56,64M)
  u16* vt = (u16*)(ws + 67108864);       // [64,72M)
  u16* attn_o = (u16*)(ws + 75497472);   // [72,80M) dead after proj
  u16* hbuf = (u16*)(ws + 50331648);     // [48,80M) FF1 out, live through FF2
  u16* pbuf = (u16*)(ws + 0);            // [0,16M)  FF2 partials (dead weights)

  dim3 tb(32, 8);
  transpose_bf16<<<dim3(3072 / 32, 1024 / 32), tb, 0, stream>>>(qkv_w, qkvwt, 1024, 3072);
  transpose_bf16<<<dim3(1024 / 32, 1024 / 32), tb, 0, stream>>>(out_w, outwt, 1024, 1024);
  transpose_bf16<<<dim3(4096 / 32, 1024 / 32), tb, 0, stream>>>(ff_w1, ffw1t, 1024, 4096);
  transpose_bf16<<<dim3(1024 / 32, 4096 / 32), tb, 0, stream>>>(ff_w2, ffw2t, 4096, 1024);

  ln_kernel<<<MMDIM, 256, 0, stream>>>(x, ln1_g, ln1_b, ln_out);
  gemm2p<0><<<dim3(3072 / 128, MMDIM / 128), 256, 0, stream>>>(
      ln_out, qkvwt, qkv_b, nullptr, qb, kb, vt, nullptr, 3072, 1024, 1024, 1024, 0);
  attn_kernel<<<dim3((TT / 32) * 32), 64, 0, stream>>>(qb, kb, vt, attn_o);
  gemm2p<1><<<dim3(1024 / 128, MMDIM / 128), 256, 0, stream>>>(
      attn_o, outwt, out_b, x, nullptr, nullptr, nullptr, x1, 1024, 1024, 1024, 1024, 0);
  ln_kernel<<<MMDIM, 256, 0, stream>>>(x1, ln2_g, ln2_b, ln_out);
  gemm2p<2><<<dim3(4096 / 128, MMDIM / 128), 256, 0, stream>>>(
      ln_out, ffw1t, ff_b1, nullptr, hbuf, nullptr, nullptr, nullptr, 4096, 1024, 1024, 1024, 0);
  gemm2p<4><<<dim3(1024 / 128, MMDIM / 128, 2), 256, 0, stream>>>(
      hbuf, ffw2t, nullptr, nullptr, pbuf, nullptr, nullptr, nullptr, 1024, 2048, 4096, 4096,
      MMDIM * E);
  ff2_reduce<<<(size_t)MMDIM * E / 1024, 256, 0, stream>>>(pbuf, pbuf + (size_t)MMDIM * E,
                                                           ff_b2, x1, (float*)d_out);
}